// Round 4
// baseline (241.898 us; speedup 1.0000x reference)
//
#include <hip/hip_runtime.h>
#include <cstddef>

#define NREL 8
#define SCAN_TILE 4096

typedef __bf16 bf16x8 __attribute__((ext_vector_type(8)));
typedef float f32x4 __attribute__((ext_vector_type(4)));

__device__ __forceinline__ unsigned f2bf_u(float f) {
    unsigned u = __float_as_uint(f);
    u += 0x7FFFu + ((u >> 16) & 1u);           // RNE
    return u >> 16;
}
__device__ __forceinline__ short f2bf(float f) { return (short)f2bf_u(f); }
__device__ __forceinline__ int pack2bf(float lo, float hi) {
    return (int)(f2bf_u(lo) | (f2bf_u(hi) << 16));
}
__device__ __forceinline__ float bf_lo(int w) { return __uint_as_float((unsigned)w << 16); }
__device__ __forceinline__ float bf_hi(int w) { return __uint_as_float((unsigned)w & 0xffff0000u); }

// ---------------------------------------------------------------------------
// Histogram per (dst, relation): cnt8[dst*8+rel]++   (cnt8 pre-zeroed)
// ---------------------------------------------------------------------------
__global__ __launch_bounds__(256) void hist_kernel(const int* __restrict__ dst,
                                                   const int* __restrict__ et,
                                                   int* __restrict__ cnt8, int E)
{
    int e = blockIdx.x * 256 + threadIdx.x;
    if (e < E) atomicAdd(&cnt8[dst[e] * NREL + et[e]], 1);
}

// ---------------------------------------------------------------------------
// Scan stage 1: per-tile degree sums
// ---------------------------------------------------------------------------
__global__ __launch_bounds__(256) void scan_part(const int* __restrict__ cnt8,
                                                 int* __restrict__ tsum, int n)
{
    int base = blockIdx.x * SCAN_TILE;
    int s = 0;
    for (int i = threadIdx.x; i < SCAN_TILE; i += 256) {
        int idx = base + i;
        if (idx < n) {
            int4 a = ((const int4*)cnt8)[idx * 2];
            int4 b = ((const int4*)cnt8)[idx * 2 + 1];
            s += a.x + a.y + a.z + a.w + b.x + b.y + b.z + b.w;
        }
    }
    for (int d = 1; d < 64; d <<= 1) s += __shfl_xor(s, d, 64);
    __shared__ int ws[4];
    if ((threadIdx.x & 63) == 0) ws[threadIdx.x >> 6] = s;
    __syncthreads();
    if (threadIdx.x == 0) tsum[blockIdx.x] = ws[0] + ws[1] + ws[2] + ws[3];
}

// ---------------------------------------------------------------------------
// Scan stage 2: serial exclusive scan of tile sums
// ---------------------------------------------------------------------------
__global__ void scan_mid(int* __restrict__ tsum, int* __restrict__ offs_n, int nt)
{
    if (threadIdx.x == 0) {
        int run = 0;
        for (int i = 0; i < nt; ++i) { int t = tsum[i]; tsum[i] = run; run += t; }
        *offs_n = run;
    }
}

// ---------------------------------------------------------------------------
// Scan stage 3: per-tile exclusive scan + tile offset -> offs[n]
// ---------------------------------------------------------------------------
__global__ __launch_bounds__(256) void scan_final(const int* __restrict__ cnt8,
                                                  const int* __restrict__ tsum,
                                                  int* __restrict__ offs, int n)
{
    const int lane = threadIdx.x & 63, wid = threadIdx.x >> 6;
    int base = blockIdx.x * SCAN_TILE + threadIdx.x * 16;
    int v[16]; int s = 0;
#pragma unroll
    for (int j = 0; j < 16; ++j) {
        int idx = base + j;
        int dv = 0;
        if (idx < n) {
            int4 a = ((const int4*)cnt8)[idx * 2];
            int4 b = ((const int4*)cnt8)[idx * 2 + 1];
            dv = a.x + a.y + a.z + a.w + b.x + b.y + b.z + b.w;
        }
        v[j] = dv; s += dv;
    }
    int inc = s;
    for (int d = 1; d < 64; d <<= 1) {
        int t = __shfl_up(inc, d, 64);
        if (lane >= d) inc += t;
    }
    __shared__ int wsum[4];
    if (lane == 63) wsum[wid] = inc;
    __syncthreads();
    int run = tsum[blockIdx.x] + (inc - s);
    for (int k = 0; k < wid; ++k) run += wsum[k];
#pragma unroll
    for (int j = 0; j < 16; ++j) {
        int idx = base + j;
        if (idx < n) offs[idx] = run;
        run += v[j];
    }
}

// ---------------------------------------------------------------------------
// Scatter edges into dst-bucketed order; edgeP = {src|rel<<29, bits(1/cnt)}
// ---------------------------------------------------------------------------
__global__ __launch_bounds__(256) void scatter_kernel(const int* __restrict__ src,
                                                      const int* __restrict__ dst,
                                                      const int* __restrict__ et,
                                                      const int* __restrict__ offs,
                                                      int* __restrict__ cursor,
                                                      const int* __restrict__ cnt8,
                                                      int2* __restrict__ edgeP, int E)
{
    int e = blockIdx.x * 256 + threadIdx.x;
    if (e >= E) return;
    int d = dst[e], r = et[e], s = src[e];
    int c = cnt8[d * NREL + r];
    float inv = 1.0f / (float)(c > 1 ? c : 1);
    int pos = offs[d] + atomicAdd(&cursor[d], 1);
    edgeP[pos] = make_int2(s | (r << 29), __float_as_int(inv));
}

// ---------------------------------------------------------------------------
// Prepack W = [basis | root] into MFMA B-fragment order:
// Wf[((t*NK+ks)*64 + lane)*8 + e] = W[k = ks*32+(lane>>4)*8+e][col = t*16+(lane&15)]
// ---------------------------------------------------------------------------
template<int K>
__global__ __launch_bounds__(256) void wfrag_kernel(const float* __restrict__ basis,
                                                    const float* __restrict__ root,
                                                    short* __restrict__ Wf)
{
    constexpr int NK = K / 32;
    int tid = blockIdx.x * 256 + threadIdx.x;
    if (tid >= 20 * NK * 64) return;
    int lane = tid & 63, slot = tid >> 6;
    int ks = slot % NK, t = slot / NK;
    int kg = lane >> 4, lr = lane & 15;
    int col = t * 16 + lr, k0 = ks * 32 + kg * 8;
    union { short s[8]; int4 v; } u;
#pragma unroll
    for (int e = 0; e < 8; ++e) {
        int k = k0 + e;
        float v = (col < 256) ? basis[((size_t)(col >> 6) * K + k) * 64 + (col & 63)]
                              : root[(size_t)k * 64 + (col - 256)];
        u.s[e] = f2bf(v);
    }
    *(int4*)(Wf + (size_t)tid * 8) = u.v;
}

// ---------------------------------------------------------------------------
// Fragment-ize x: f32 row-major -> bf16 A-fragment order, zero-pad rows >= N.
// xf[((rt*NK+ks)*64 + lane)*8 + e] = x[row = rt*16+(lane&15)][k = ks*32+(lane>>4)*8+e]
// ---------------------------------------------------------------------------
template<int K>
__global__ __launch_bounds__(256) void afrag_kernel(const float* __restrict__ x,
                                                    short* __restrict__ xf,
                                                    int N, int NT)
{
    constexpr int NK = K / 32;
    int tid = blockIdx.x * 256 + threadIdx.x;
    if (tid >= NT * NK * 64) return;
    int lane = tid & 63, slot = tid >> 6;
    int ks = slot % NK, rt = slot / NK;
    int kg = lane >> 4, lr = lane & 15;
    int row = rt * 16 + lr, k = ks * 32 + kg * 8;
    union { short s[8]; int4 v; } u;
    if (row < N) {
        const float* xp = x + (size_t)row * K + k;
        float4 a = *(const float4*)xp;
        float4 b = *(const float4*)(xp + 4);
        u.s[0] = f2bf(a.x); u.s[1] = f2bf(a.y); u.s[2] = f2bf(a.z); u.s[3] = f2bf(a.w);
        u.s[4] = f2bf(b.x); u.s[5] = f2bf(b.y); u.s[6] = f2bf(b.z); u.s[7] = f2bf(b.w);
    } else {
        u.v = make_int4(0, 0, 0, 0);
    }
    *(int4*)(xf + (size_t)tid * 8) = u.v;
}

// ---------------------------------------------------------------------------
// Fused basis+root GEMM, all operands pre-swizzled to fragment order.
// Wave w of block b owns row-tile rt = b*4+w (16 rows) x 320 cols.
// Every load is a fully-contiguous 1024B wave load.
// Cols 0..255 -> h4[n][c][b] (packed int2), cols 256..319 -> yinit[n][64]+bias.
// ---------------------------------------------------------------------------
template<int K>
__global__ __launch_bounds__(256) void gemm_mfma(const short* __restrict__ xf,
                                                 const short* __restrict__ Wf,
                                                 const float* __restrict__ bias,
                                                 short* __restrict__ h4,
                                                 float* __restrict__ yinit, int N)
{
    constexpr int NK = K / 32;
    const int w = threadIdx.x >> 6, lane = threadIdx.x & 63;
    const int kg = lane >> 4, lr = lane & 15;
    const int rt = blockIdx.x * 4 + w;

    bf16x8 afrag[NK];
    const short* ap = xf + ((size_t)rt * NK * 64 + lane) * 8;
#pragma unroll
    for (int ks = 0; ks < NK; ++ks)
        afrag[ks] = *(const bf16x8*)(ap + ks * 512);

    f32x4 acc[20];
#pragma unroll
    for (int t = 0; t < 20; ++t) acc[t] = (f32x4){0.f, 0.f, 0.f, 0.f};

    const short* bp = Wf + (size_t)lane * 8;
#pragma unroll
    for (int t = 0; t < 20; ++t) {
#pragma unroll
        for (int ks = 0; ks < NK; ++ks) {
            bf16x8 bfrag = *(const bf16x8*)(bp + (size_t)(t * NK + ks) * 512);
            acc[t] = __builtin_amdgcn_mfma_f32_16x16x32_bf16(afrag[ks], bfrag, acc[t], 0, 0, 0);
        }
    }

    const int drow0 = rt * 16 + kg * 4;
#pragma unroll
    for (int r = 0; r < 4; ++r) {
        int dr = drow0 + r;
        if (dr >= N) break;
#pragma unroll
        for (int c4 = 0; c4 < 4; ++c4) {
            int u0 = pack2bf(acc[c4][r],     acc[c4 + 4][r]);
            int u1 = pack2bf(acc[c4 + 8][r], acc[c4 + 12][r]);
            *(int2*)(h4 + (size_t)dr * 256 + (c4 * 16 + lr) * 4) = make_int2(u0, u1);
        }
#pragma unroll
        for (int t = 16; t < 20; ++t) {
            int c = (t - 16) * 16 + lr;
            yinit[(size_t)dr * 64 + c] = acc[t][r] + bias[c];
        }
    }
}

// ---------------------------------------------------------------------------
// Aggregate: one 64-lane slice per dst node, lane = channel. Register
// accumulation over the node's bucketed edges; one store per node.
// Layer 1 (BF16OUT): store relu(acc) as bf16 directly in layer-2 A-fragment
// order (K=64, NK=2). Layer 2: f32 row-major to d_out.
// ---------------------------------------------------------------------------
template<bool BF16OUT>
__global__ __launch_bounds__(256) void agg_kernel(const int* __restrict__ offs,
                                                  const int2* __restrict__ edgeP,
                                                  const float* __restrict__ comp,
                                                  const short* __restrict__ h4,
                                                  const float* __restrict__ init,
                                                  float* __restrict__ outF,
                                                  short* __restrict__ outB, int N)
{
    __shared__ float4 compS[NREL];
    if (threadIdx.x < NREL) compS[threadIdx.x] = ((const float4*)comp)[threadIdx.x];
    __syncthreads();

    const int dst = blockIdx.x * 4 + (threadIdx.x >> 6);
    const int c = threadIdx.x & 63;
    if (dst >= N) return;

    float acc = init[(size_t)dst * 64 + c];
    int e0 = offs[dst], e1 = offs[dst + 1];

    int e = e0;
    for (; e + 1 < e1; e += 2) {
        int2 pa = edgeP[e], pb = edgeP[e + 1];
        float i0 = __int_as_float(pa.y), i1 = __int_as_float(pb.y);
        int s0 = pa.x & 0x1FFFFFFF, s1 = pb.x & 0x1FFFFFFF;
        float4 w0 = compS[(unsigned)pa.x >> 29];
        float4 w1 = compS[(unsigned)pb.x >> 29];
        int2 ha = *(const int2*)(h4 + (size_t)s0 * 256 + c * 4);
        int2 hb = *(const int2*)(h4 + (size_t)s1 * 256 + c * 4);
        acc += (w0.x * bf_lo(ha.x) + w0.y * bf_hi(ha.x) +
                w0.z * bf_lo(ha.y) + w0.w * bf_hi(ha.y)) * i0;
        acc += (w1.x * bf_lo(hb.x) + w1.y * bf_hi(hb.x) +
                w1.z * bf_lo(hb.y) + w1.w * bf_hi(hb.y)) * i1;
    }
    if (e < e1) {
        int2 pa = edgeP[e];
        float i0 = __int_as_float(pa.y);
        int s0 = pa.x & 0x1FFFFFFF;
        float4 w0 = compS[(unsigned)pa.x >> 29];
        int2 ha = *(const int2*)(h4 + (size_t)s0 * 256 + c * 4);
        acc += (w0.x * bf_lo(ha.x) + w0.y * bf_hi(ha.x) +
                w0.z * bf_lo(ha.y) + w0.w * bf_hi(ha.y)) * i0;
    }

    if (BF16OUT) {
        // write into layer-2 A-fragment layout (K=64, NK=2)
        int rt2 = dst >> 4, lr2 = dst & 15;
        int ks2 = c >> 5, kg2 = (c >> 3) & 3, e2 = c & 7;
        outB[(((size_t)rt2 * 2 + ks2) * 64 + kg2 * 16 + lr2) * 8 + e2] =
            f2bf(fmaxf(acc, 0.f));
    } else {
        outF[(size_t)dst * 64 + c] = acc;
    }
}

// ---------------------------------------------------------------------------
extern "C" void kernel_launch(void* const* d_in, const int* in_sizes, int n_in,
                              void* d_out, int out_size, void* d_ws, size_t ws_size,
                              hipStream_t stream)
{
    const float* x      = (const float*)d_in[0];
    const int*   ei     = (const int*)d_in[1];
    const int*   et     = (const int*)d_in[2];
    const float* basis1 = (const float*)d_in[3];
    const float* comp1  = (const float*)d_in[4];
    const float* root1  = (const float*)d_in[5];
    const float* bias1  = (const float*)d_in[6];
    const float* basis2 = (const float*)d_in[7];
    const float* comp2  = (const float*)d_in[8];
    const float* root2  = (const float*)d_in[9];
    const float* bias2  = (const float*)d_in[10];
    float* out = (float*)d_out;

    const int N = in_sizes[0] / 128;
    const int E = in_sizes[2];
    const int* src  = ei;
    const int* dstp = ei + E;

    const int gblk = (N + 63) / 64;   // gemm blocks
    const int NT   = gblk * 4;        // padded 16-row tiles
    const int ablk = (N + 3) / 4;

    // -------- workspace carve (256B aligned) --------
    char* p = (char*)d_ws;
    auto carve = [&](size_t bytes) -> char* {
        char* q = p; p += (bytes + 255) & ~(size_t)255; return q;
    };
    int*   cursor  = (int*)carve((size_t)N * 4);          // zeroed
    int*   cnt8    = (int*)carve((size_t)N * NREL * 4);   // zeroed
    char*  zend    = p;
    int*   offs    = (int*)carve((size_t)(N + 1) * 4);
    int*   tsum    = (int*)carve(256 * 4);
    int2*  edgeP   = (int2*)carve((size_t)E * 8);
    short* Wf1     = (short*)carve((size_t)20 * 4 * 64 * 8 * 2);
    short* Wf2     = (short*)carve((size_t)20 * 2 * 64 * 8 * 2);
    float* y1init  = (float*)carve((size_t)N * 64 * 4);
    short* xf1     = (short*)carve((size_t)NT * 4 * 64 * 8 * 2);
    short* xf2     = (short*)carve((size_t)NT * 2 * 64 * 8 * 2);
    short* h4      = (short*)carve((size_t)N * 256 * 2);

    hipMemsetAsync(cursor, 0, (size_t)(zend - (char*)cursor), stream);

    const int ntiles = (N + SCAN_TILE - 1) / SCAN_TILE;

    // -------- edge bucketing (shared by both layers) --------
    hist_kernel<<<(E + 255) / 256, 256, 0, stream>>>(dstp, et, cnt8, E);
    scan_part<<<ntiles, 256, 0, stream>>>(cnt8, tsum, N);
    scan_mid<<<1, 64, 0, stream>>>(tsum, offs + N, ntiles);
    scan_final<<<ntiles, 256, 0, stream>>>(cnt8, tsum, offs, N);
    scatter_kernel<<<(E + 255) / 256, 256, 0, stream>>>(src, dstp, et, offs, cursor,
                                                        cnt8, edgeP, E);

    // -------- prepacks --------
    wfrag_kernel<128><<<(20 * 4 * 64 + 255) / 256, 256, 0, stream>>>(basis1, root1, Wf1);
    wfrag_kernel<64><<<(20 * 2 * 64 + 255) / 256, 256, 0, stream>>>(basis2, root2, Wf2);
    afrag_kernel<128><<<(NT * 4 * 64 + 255) / 256, 256, 0, stream>>>(x, xf1, N, NT);

    // -------- layer 1 --------
    gemm_mfma<128><<<gblk, 256, 0, stream>>>(xf1, Wf1, bias1, h4, y1init, N);
    agg_kernel<true><<<ablk, 256, 0, stream>>>(offs, edgeP, comp1, h4, y1init,
                                               nullptr, xf2, N);

    // -------- layer 2 --------
    gemm_mfma<64><<<gblk, 256, 0, stream>>>(xf2, Wf2, bias2, h4, out, N);
    agg_kernel<false><<<ablk, 256, 0, stream>>>(offs, edgeP, comp2, h4, out,
                                                out, nullptr, N);
}

// Round 5
// 205.476 us; speedup vs baseline: 1.1773x; 1.1773x over previous
//
#include <hip/hip_runtime.h>
#include <cstddef>

#define NREL 8
#define SCAN_TILE 4096

typedef __bf16 bf16x8 __attribute__((ext_vector_type(8)));
typedef float f32x4 __attribute__((ext_vector_type(4)));

__device__ __forceinline__ unsigned f2bf_u(float f) {
    unsigned u = __float_as_uint(f);
    u += 0x7FFFu + ((u >> 16) & 1u);           // RNE
    return u >> 16;
}
__device__ __forceinline__ short f2bf(float f) { return (short)f2bf_u(f); }
__device__ __forceinline__ int pack2bf(float lo, float hi) {
    return (int)(f2bf_u(lo) | (f2bf_u(hi) << 16));
}
__device__ __forceinline__ float bfval(unsigned short g) {
    return __uint_as_float((unsigned)g << 16);
}

// ---------------------------------------------------------------------------
// Histogram per (dst, relation): cnt8[dst*8+rel]++   (cnt8 pre-zeroed)
// ---------------------------------------------------------------------------
__global__ __launch_bounds__(256) void hist_kernel(const int* __restrict__ dst,
                                                   const int* __restrict__ et,
                                                   int* __restrict__ cnt8, int E)
{
    int e = blockIdx.x * 256 + threadIdx.x;
    if (e < E) atomicAdd(&cnt8[dst[e] * NREL + et[e]], 1);
}

// ---------------------------------------------------------------------------
// Scan stage 1: per-tile degree sums
// ---------------------------------------------------------------------------
__global__ __launch_bounds__(256) void scan_part(const int* __restrict__ cnt8,
                                                 int* __restrict__ tsum, int n)
{
    int base = blockIdx.x * SCAN_TILE;
    int s = 0;
    for (int i = threadIdx.x; i < SCAN_TILE; i += 256) {
        int idx = base + i;
        if (idx < n) {
            int4 a = ((const int4*)cnt8)[idx * 2];
            int4 b = ((const int4*)cnt8)[idx * 2 + 1];
            s += a.x + a.y + a.z + a.w + b.x + b.y + b.z + b.w;
        }
    }
    for (int d = 1; d < 64; d <<= 1) s += __shfl_xor(s, d, 64);
    __shared__ int ws[4];
    if ((threadIdx.x & 63) == 0) ws[threadIdx.x >> 6] = s;
    __syncthreads();
    if (threadIdx.x == 0) tsum[blockIdx.x] = ws[0] + ws[1] + ws[2] + ws[3];
}

// ---------------------------------------------------------------------------
// Scan stage 2: serial exclusive scan of tile sums
// ---------------------------------------------------------------------------
__global__ void scan_mid(int* __restrict__ tsum, int* __restrict__ offs_n, int nt)
{
    if (threadIdx.x == 0) {
        int run = 0;
        for (int i = 0; i < nt; ++i) { int t = tsum[i]; tsum[i] = run; run += t; }
        *offs_n = run;
    }
}

// ---------------------------------------------------------------------------
// Scan stage 3: per-tile exclusive scan + tile offset -> offs[n]
// ---------------------------------------------------------------------------
__global__ __launch_bounds__(256) void scan_final(const int* __restrict__ cnt8,
                                                  const int* __restrict__ tsum,
                                                  int* __restrict__ offs, int n)
{
    const int lane = threadIdx.x & 63, wid = threadIdx.x >> 6;
    int base = blockIdx.x * SCAN_TILE + threadIdx.x * 16;
    int v[16]; int s = 0;
#pragma unroll
    for (int j = 0; j < 16; ++j) {
        int idx = base + j;
        int dv = 0;
        if (idx < n) {
            int4 a = ((const int4*)cnt8)[idx * 2];
            int4 b = ((const int4*)cnt8)[idx * 2 + 1];
            dv = a.x + a.y + a.z + a.w + b.x + b.y + b.z + b.w;
        }
        v[j] = dv; s += dv;
    }
    int inc = s;
    for (int d = 1; d < 64; d <<= 1) {
        int t = __shfl_up(inc, d, 64);
        if (lane >= d) inc += t;
    }
    __shared__ int wsum[4];
    if (lane == 63) wsum[wid] = inc;
    __syncthreads();
    int run = tsum[blockIdx.x] + (inc - s);
    for (int k = 0; k < wid; ++k) run += wsum[k];
#pragma unroll
    for (int j = 0; j < 16; ++j) {
        int idx = base + j;
        if (idx < n) offs[idx] = run;
        run += v[j];
    }
}

// ---------------------------------------------------------------------------
// Scatter edges into dst-bucketed order; edgeP = {src*8+rel, bits(1/cnt)}
// ---------------------------------------------------------------------------
__global__ __launch_bounds__(256) void scatter_kernel(const int* __restrict__ src,
                                                      const int* __restrict__ dst,
                                                      const int* __restrict__ et,
                                                      const int* __restrict__ offs,
                                                      int* __restrict__ cursor,
                                                      const int* __restrict__ cnt8,
                                                      int2* __restrict__ edgeP, int E)
{
    int e = blockIdx.x * 256 + threadIdx.x;
    if (e >= E) return;
    int d = dst[e], r = et[e], s = src[e];
    int c = cnt8[d * NREL + r];
    float inv = 1.0f / (float)(c > 1 ? c : 1);
    int pos = offs[d] + atomicAdd(&cursor[d], 1);
    edgeP[pos] = make_int2(s * NREL + r, __float_as_int(inv));
}

// ---------------------------------------------------------------------------
// Prepack W' into MFMA B-fragment order, comp folded in. 36 col-tiles:
//   t = 0..31:  rel rr = t>>2, true channel ch = (t&3)*16 + lr;
//               W'[k][t*16+lr] = sum_b comp[rr][b] * basis[b][k][ch]
//   t = 32..35: root[k][(t-32)*16 + lr]
// Wf[((t*NK+ks)*64 + lane)*8 + e], k = ks*32 + (lane>>4)*8 + e
// ---------------------------------------------------------------------------
template<int K>
__global__ __launch_bounds__(256) void wfrag_kernel(const float* __restrict__ basis,
                                                    const float* __restrict__ root,
                                                    const float* __restrict__ comp,
                                                    short* __restrict__ Wf)
{
    constexpr int NK = K / 32;
    int tid = blockIdx.x * 256 + threadIdx.x;
    if (tid >= 36 * NK * 64) return;
    int lane = tid & 63, slot = tid >> 6;
    int ks = slot % NK, t = slot / NK;
    int kg = lane >> 4, lr = lane & 15;
    int k0 = ks * 32 + kg * 8;
    union { short s[8]; int4 v; } u;
#pragma unroll
    for (int e = 0; e < 8; ++e) {
        int k = k0 + e;
        float v;
        if (t < 32) {
            int rr = t >> 2, ch = (t & 3) * 16 + lr;
            v = comp[rr * 4 + 0] * basis[((size_t)0 * K + k) * 64 + ch]
              + comp[rr * 4 + 1] * basis[((size_t)1 * K + k) * 64 + ch]
              + comp[rr * 4 + 2] * basis[((size_t)2 * K + k) * 64 + ch]
              + comp[rr * 4 + 3] * basis[((size_t)3 * K + k) * 64 + ch];
        } else {
            v = root[(size_t)k * 64 + (t - 32) * 16 + lr];
        }
        u.s[e] = f2bf(v);
    }
    *(int4*)(Wf + (size_t)tid * 8) = u.v;
}

// ---------------------------------------------------------------------------
// Fused all-relation + root GEMM: [N,K] x [K,576], B LDS-staged per block.
// Wave w of block b owns row-tile rt = b*4+w (16 rows) x all 576 cols.
// Epilogue (permuted channel slots c' = lr*4 + tt, true ch = tt*16 + lr):
//   tiles 0..31 -> hr[n][rr*64 + c'] bf16 (coalesced int2)
//   tiles 32..35 -> yinit[n][c'] = root+bias f32 (coalesced float4)
// A-side: AF32 gathers/converts from row-major f32 x; else pre-fragmented bf16.
// ---------------------------------------------------------------------------
template<int K, bool AF32>
__global__ __launch_bounds__(256, 1) void gemm_mfma(const void* __restrict__ Ap,
                                                    const short* __restrict__ Wf,
                                                    const float* __restrict__ bias,
                                                    short* __restrict__ hr,
                                                    float* __restrict__ yinit, int N)
{
    constexpr int NK = K / 32;
    constexpr int CH = 9;                       // col-tiles per LDS chunk (36 = 4*9)
    __shared__ short lds[CH * NK * 512];        // CH*NK*1024 bytes

    const int w = threadIdx.x >> 6, lane = threadIdx.x & 63;
    const int kg = lane >> 4, lr = lane & 15;
    const int rt = blockIdx.x * 4 + w;

    bf16x8 afrag[NK];
    if (AF32) {
        const float* A = (const float*)Ap;
        int arow = rt * 16 + lr;
        int ar = arow < N ? arow : N - 1;
#pragma unroll
        for (int ks = 0; ks < NK; ++ks) {
            const float* ap = A + (size_t)ar * K + ks * 32 + kg * 8;
            float4 a = *(const float4*)ap;
            float4 b = *(const float4*)(ap + 4);
            union { short s[8]; bf16x8 v; } cv;
            cv.s[0] = f2bf(a.x); cv.s[1] = f2bf(a.y); cv.s[2] = f2bf(a.z); cv.s[3] = f2bf(a.w);
            cv.s[4] = f2bf(b.x); cv.s[5] = f2bf(b.y); cv.s[6] = f2bf(b.z); cv.s[7] = f2bf(b.w);
            afrag[ks] = cv.v;
        }
    } else {
        const short* A = (const short*)Ap;
        const short* ap = A + ((size_t)rt * NK * 64 + lane) * 8;
#pragma unroll
        for (int ks = 0; ks < NK; ++ks)
            afrag[ks] = *(const bf16x8*)(ap + ks * 512);
    }

    f32x4 acc[36];
#pragma unroll
    for (int t = 0; t < 36; ++t) acc[t] = (f32x4){0.f, 0.f, 0.f, 0.f};

    for (int c = 0; c < 4; ++c) {
        const int4* gsrc = (const int4*)(Wf + (size_t)c * CH * NK * 512);
        int4* ldst = (int4*)lds;
        for (int i = threadIdx.x; i < CH * NK * 64; i += 256)
            ldst[i] = gsrc[i];
        __syncthreads();
#pragma unroll
        for (int tt = 0; tt < CH; ++tt) {
#pragma unroll
            for (int ks = 0; ks < NK; ++ks) {
                bf16x8 bfrag = *(const bf16x8*)(lds + (tt * NK + ks) * 512 + lane * 8);
                acc[c * CH + tt] = __builtin_amdgcn_mfma_f32_16x16x32_bf16(
                    afrag[ks], bfrag, acc[c * CH + tt], 0, 0, 0);
            }
        }
        __syncthreads();
    }

    // permuted bias for root slots: slot c' = lr*4 + tt2 holds ch = tt2*16 + lr
    float b0 = bias[lr], b1 = bias[16 + lr], b2 = bias[32 + lr], b3 = bias[48 + lr];

    const int drow0 = rt * 16 + kg * 4;
#pragma unroll
    for (int r = 0; r < 4; ++r) {
        int dr = drow0 + r;
        if (dr >= N) break;
#pragma unroll
        for (int rr = 0; rr < 8; ++rr) {
            int u0 = pack2bf(acc[rr * 4 + 0][r], acc[rr * 4 + 1][r]);
            int u1 = pack2bf(acc[rr * 4 + 2][r], acc[rr * 4 + 3][r]);
            *(int2*)(hr + (size_t)dr * 512 + rr * 64 + lr * 4) = make_int2(u0, u1);
        }
        float4 o = make_float4(acc[32][r] + b0, acc[33][r] + b1,
                               acc[34][r] + b2, acc[35][r] + b3);
        *(float4*)(yinit + (size_t)dr * 64 + lr * 4) = o;
    }
}

// ---------------------------------------------------------------------------
// Aggregate: one 64-lane slice per dst node, lane = permuted channel slot.
// Per edge: gather 64 bf16 (128B contiguous) at hr[p.x*64 + lane], fma by inv.
// 4-deep unroll -> 4 independent outstanding gathers.
// Epilogue converts slot -> true channel tc = (l&3)*16 + (l>>2).
// ---------------------------------------------------------------------------
template<bool BF16OUT>
__global__ __launch_bounds__(256) void agg_kernel(const int* __restrict__ offs,
                                                  const int2* __restrict__ edgeP,
                                                  const short* __restrict__ hr,
                                                  const float* __restrict__ init,
                                                  float* __restrict__ outF,
                                                  short* __restrict__ outB, int N)
{
    const int dst = blockIdx.x * 4 + (threadIdx.x >> 6);
    const int l = threadIdx.x & 63;
    if (dst >= N) return;

    const unsigned short* hp = (const unsigned short*)hr;
    float acc = init[(size_t)dst * 64 + l];
    int e0 = offs[dst], e1 = offs[dst + 1];

    int e = e0;
    for (; e + 3 < e1; e += 4) {
        int2 p0 = edgeP[e],     p1 = edgeP[e + 1];
        int2 p2 = edgeP[e + 2], p3 = edgeP[e + 3];
        unsigned short g0 = hp[(size_t)p0.x * 64 + l];
        unsigned short g1 = hp[(size_t)p1.x * 64 + l];
        unsigned short g2 = hp[(size_t)p2.x * 64 + l];
        unsigned short g3 = hp[(size_t)p3.x * 64 + l];
        acc = fmaf(bfval(g0), __int_as_float(p0.y), acc);
        acc = fmaf(bfval(g1), __int_as_float(p1.y), acc);
        acc = fmaf(bfval(g2), __int_as_float(p2.y), acc);
        acc = fmaf(bfval(g3), __int_as_float(p3.y), acc);
    }
    for (; e < e1; ++e) {
        int2 p0 = edgeP[e];
        unsigned short g0 = hp[(size_t)p0.x * 64 + l];
        acc = fmaf(bfval(g0), __int_as_float(p0.y), acc);
    }

    int tc = (l & 3) * 16 + (l >> 2);    // true channel
    if (BF16OUT) {
        // layer-2 A-fragment layout (K=64, NK=2), k = true channel
        int rt2 = dst >> 4, lr2 = dst & 15;
        int ks2 = tc >> 5, kg2 = (tc >> 3) & 3, e2 = tc & 7;
        outB[(((size_t)rt2 * 2 + ks2) * 64 + kg2 * 16 + lr2) * 8 + e2] =
            f2bf(fmaxf(acc, 0.f));
    } else {
        outF[(size_t)dst * 64 + tc] = acc;
    }
}

// ---------------------------------------------------------------------------
extern "C" void kernel_launch(void* const* d_in, const int* in_sizes, int n_in,
                              void* d_out, int out_size, void* d_ws, size_t ws_size,
                              hipStream_t stream)
{
    const float* x      = (const float*)d_in[0];
    const int*   ei     = (const int*)d_in[1];
    const int*   et     = (const int*)d_in[2];
    const float* basis1 = (const float*)d_in[3];
    const float* comp1  = (const float*)d_in[4];
    const float* root1  = (const float*)d_in[5];
    const float* bias1  = (const float*)d_in[6];
    const float* basis2 = (const float*)d_in[7];
    const float* comp2  = (const float*)d_in[8];
    const float* root2  = (const float*)d_in[9];
    const float* bias2  = (const float*)d_in[10];
    float* out = (float*)d_out;

    const int N = in_sizes[0] / 128;
    const int E = in_sizes[2];
    const int* src  = ei;
    const int* dstp = ei + E;

    const int gblk = (N + 63) / 64;
    const int NT   = gblk * 4;
    const int ablk = (N + 3) / 4;

    // -------- workspace carve (256B aligned) --------
    char* p = (char*)d_ws;
    auto carve = [&](size_t bytes) -> char* {
        char* q = p; p += (bytes + 255) & ~(size_t)255; return q;
    };
    int*   cursor  = (int*)carve((size_t)N * 4);          // zeroed
    int*   cnt8    = (int*)carve((size_t)N * NREL * 4);   // zeroed
    char*  zend    = p;
    int*   offs    = (int*)carve((size_t)(N + 1) * 4);
    int*   tsum    = (int*)carve(256 * 4);
    int2*  edgeP   = (int2*)carve((size_t)E * 8);
    short* Wf1     = (short*)carve((size_t)36 * 4 * 64 * 8 * 2);
    short* Wf2     = (short*)carve((size_t)36 * 2 * 64 * 8 * 2);
    float* yinit   = (float*)carve((size_t)N * 64 * 4);
    short* xf2     = (short*)carve((size_t)NT * 2 * 64 * 8 * 2);
    short* hr      = (short*)carve((size_t)N * 512 * 2);

    hipMemsetAsync(cursor, 0, (size_t)(zend - (char*)cursor), stream);

    const int ntiles = (N + SCAN_TILE - 1) / SCAN_TILE;

    // -------- edge bucketing (shared by both layers) --------
    hist_kernel<<<(E + 255) / 256, 256, 0, stream>>>(dstp, et, cnt8, E);
    scan_part<<<ntiles, 256, 0, stream>>>(cnt8, tsum, N);
    scan_mid<<<1, 64, 0, stream>>>(tsum, offs + N, ntiles);
    scan_final<<<ntiles, 256, 0, stream>>>(cnt8, tsum, offs, N);
    scatter_kernel<<<(E + 255) / 256, 256, 0, stream>>>(src, dstp, et, offs, cursor,
                                                        cnt8, edgeP, E);

    // -------- weight prepacks (comp folded in) --------
    wfrag_kernel<128><<<(36 * 4 * 64 + 255) / 256, 256, 0, stream>>>(basis1, root1, comp1, Wf1);
    wfrag_kernel<64><<<(36 * 2 * 64 + 255) / 256, 256, 0, stream>>>(basis2, root2, comp2, Wf2);

    // -------- layer 1 --------
    gemm_mfma<128, true><<<gblk, 256, 0, stream>>>(x, Wf1, bias1, hr, yinit, N);
    agg_kernel<true><<<ablk, 256, 0, stream>>>(offs, edgeP, hr, yinit, nullptr, xf2, N);

    // -------- layer 2 --------
    gemm_mfma<64, false><<<gblk, 256, 0, stream>>>(xf2, Wf2, bias2, hr, yinit, N);
    agg_kernel<false><<<ablk, 256, 0, stream>>>(offs, edgeP, hr, yinit, out, nullptr, N);
}

// Round 6
// 200.179 us; speedup vs baseline: 1.2084x; 1.0265x over previous
//
#include <hip/hip_runtime.h>
#include <cstddef>

#define NREL 8
#define SCAN_TILE 4096

typedef __bf16 bf16x8 __attribute__((ext_vector_type(8)));
typedef float f32x4 __attribute__((ext_vector_type(4)));

__device__ __forceinline__ unsigned f2bf_u(float f) {
    unsigned u = __float_as_uint(f);
    u += 0x7FFFu + ((u >> 16) & 1u);           // RNE
    return u >> 16;
}
__device__ __forceinline__ short f2bf(float f) { return (short)f2bf_u(f); }
__device__ __forceinline__ int pack2bf(float lo, float hi) {
    return (int)(f2bf_u(lo) | (f2bf_u(hi) << 16));
}
__device__ __forceinline__ float bfval(unsigned short g) {
    return __uint_as_float((unsigned)g << 16);
}

// ---------------------------------------------------------------------------
// Histogram per (dst, relation): cnt8[dst*8+rel]++   (cnt8 pre-zeroed)
// ---------------------------------------------------------------------------
__global__ __launch_bounds__(256) void hist_kernel(const int* __restrict__ dst,
                                                   const int* __restrict__ et,
                                                   int* __restrict__ cnt8, int E)
{
    int e = blockIdx.x * 256 + threadIdx.x;
    if (e < E) atomicAdd(&cnt8[dst[e] * NREL + et[e]], 1);
}

// ---------------------------------------------------------------------------
// Scan stage 1: per-tile degree sums
// ---------------------------------------------------------------------------
__global__ __launch_bounds__(256) void scan_part(const int* __restrict__ cnt8,
                                                 int* __restrict__ tsum, int n)
{
    int base = blockIdx.x * SCAN_TILE;
    int s = 0;
    for (int i = threadIdx.x; i < SCAN_TILE; i += 256) {
        int idx = base + i;
        if (idx < n) {
            int4 a = ((const int4*)cnt8)[idx * 2];
            int4 b = ((const int4*)cnt8)[idx * 2 + 1];
            s += a.x + a.y + a.z + a.w + b.x + b.y + b.z + b.w;
        }
    }
    for (int d = 1; d < 64; d <<= 1) s += __shfl_xor(s, d, 64);
    __shared__ int ws[4];
    if ((threadIdx.x & 63) == 0) ws[threadIdx.x >> 6] = s;
    __syncthreads();
    if (threadIdx.x == 0) tsum[blockIdx.x] = ws[0] + ws[1] + ws[2] + ws[3];
}

// ---------------------------------------------------------------------------
// Scan stage 2: serial exclusive scan of tile sums
// ---------------------------------------------------------------------------
__global__ void scan_mid(int* __restrict__ tsum, int* __restrict__ offs_n, int nt)
{
    if (threadIdx.x == 0) {
        int run = 0;
        for (int i = 0; i < nt; ++i) { int t = tsum[i]; tsum[i] = run; run += t; }
        *offs_n = run;
    }
}

// ---------------------------------------------------------------------------
// Scan stage 3: per-tile exclusive scan + tile offset -> offs[n]
// ---------------------------------------------------------------------------
__global__ __launch_bounds__(256) void scan_final(const int* __restrict__ cnt8,
                                                  const int* __restrict__ tsum,
                                                  int* __restrict__ offs, int n)
{
    const int lane = threadIdx.x & 63, wid = threadIdx.x >> 6;
    int base = blockIdx.x * SCAN_TILE + threadIdx.x * 16;
    int v[16]; int s = 0;
#pragma unroll
    for (int j = 0; j < 16; ++j) {
        int idx = base + j;
        int dv = 0;
        if (idx < n) {
            int4 a = ((const int4*)cnt8)[idx * 2];
            int4 b = ((const int4*)cnt8)[idx * 2 + 1];
            dv = a.x + a.y + a.z + a.w + b.x + b.y + b.z + b.w;
        }
        v[j] = dv; s += dv;
    }
    int inc = s;
    for (int d = 1; d < 64; d <<= 1) {
        int t = __shfl_up(inc, d, 64);
        if (lane >= d) inc += t;
    }
    __shared__ int wsum[4];
    if (lane == 63) wsum[wid] = inc;
    __syncthreads();
    int run = tsum[blockIdx.x] + (inc - s);
    for (int k = 0; k < wid; ++k) run += wsum[k];
#pragma unroll
    for (int j = 0; j < 16; ++j) {
        int idx = base + j;
        if (idx < n) offs[idx] = run;
        run += v[j];
    }
}

// ---------------------------------------------------------------------------
// Scatter edges into dst-bucketed order; edgeP = {src*8+rel, bits(1/cnt)}
// ---------------------------------------------------------------------------
__global__ __launch_bounds__(256) void scatter_kernel(const int* __restrict__ src,
                                                      const int* __restrict__ dst,
                                                      const int* __restrict__ et,
                                                      const int* __restrict__ offs,
                                                      int* __restrict__ cursor,
                                                      const int* __restrict__ cnt8,
                                                      int2* __restrict__ edgeP, int E)
{
    int e = blockIdx.x * 256 + threadIdx.x;
    if (e >= E) return;
    int d = dst[e], r = et[e], s = src[e];
    int c = cnt8[d * NREL + r];
    float inv = 1.0f / (float)(c > 1 ? c : 1);
    int pos = offs[d] + atomicAdd(&cursor[d], 1);
    edgeP[pos] = make_int2(s * NREL + r, __float_as_int(inv));
}

// ---------------------------------------------------------------------------
// Prepack W' into MFMA B-fragment order, comp folded in. 36 col-tiles:
//   t = 0..31:  rel rr = t>>2, true channel ch = (t&3)*16 + lr;
//               W'[k][t*16+lr] = sum_b comp[rr][b] * basis[b][k][ch]
//   t = 32..35: root[k][(t-32)*16 + lr]
// Wf[((t*NK+ks)*64 + lane)*8 + e], k = ks*32 + (lane>>4)*8 + e
// ---------------------------------------------------------------------------
template<int K>
__global__ __launch_bounds__(256) void wfrag_kernel(const float* __restrict__ basis,
                                                    const float* __restrict__ root,
                                                    const float* __restrict__ comp,
                                                    short* __restrict__ Wf)
{
    constexpr int NK = K / 32;
    int tid = blockIdx.x * 256 + threadIdx.x;
    if (tid >= 36 * NK * 64) return;
    int lane = tid & 63, slot = tid >> 6;
    int ks = slot % NK, t = slot / NK;
    int kg = lane >> 4, lr = lane & 15;
    int k0 = ks * 32 + kg * 8;
    union { short s[8]; int4 v; } u;
#pragma unroll
    for (int e = 0; e < 8; ++e) {
        int k = k0 + e;
        float v;
        if (t < 32) {
            int rr = t >> 2, ch = (t & 3) * 16 + lr;
            v = comp[rr * 4 + 0] * basis[((size_t)0 * K + k) * 64 + ch]
              + comp[rr * 4 + 1] * basis[((size_t)1 * K + k) * 64 + ch]
              + comp[rr * 4 + 2] * basis[((size_t)2 * K + k) * 64 + ch]
              + comp[rr * 4 + 3] * basis[((size_t)3 * K + k) * 64 + ch];
        } else {
            v = root[(size_t)k * 64 + (t - 32) * 16 + lr];
        }
        u.s[e] = f2bf(v);
    }
    *(int4*)(Wf + (size_t)tid * 8) = u.v;
}

// ---------------------------------------------------------------------------
// Fused all-relation + root GEMM: [N,K] x [K,576], split over blockIdx.y.
// Block (bx, by): rows bx*64..+63 (wave w -> row-tile rt = bx*4+w), col
// groups by*3..by*3+2 (group g<8 = rel g, tiles g*4..g*4+3; g==8 = root).
// No LDS: B fragments loaded directly (contiguous 1024B wave loads, identical
// across waves -> L2 broadcast). acc[12] keeps regs low for occupancy.
// Epilogue (permuted channel slots c' = lr*4 + tt, true ch = tt*16 + lr):
//   rel groups  -> hr[n][g*64 + c'] bf16 (coalesced int2)
//   root group  -> yinit[n][c'] = root+bias f32 (coalesced float4)
// ---------------------------------------------------------------------------
template<int K, bool AF32>
__global__ __launch_bounds__(256) void gemm_mfma(const void* __restrict__ Ap,
                                                 const short* __restrict__ Wf,
                                                 const float* __restrict__ bias,
                                                 short* __restrict__ hr,
                                                 float* __restrict__ yinit, int N)
{
    constexpr int NK = K / 32;
    const int w = threadIdx.x >> 6, lane = threadIdx.x & 63;
    const int kg = lane >> 4, lr = lane & 15;
    const int rt = blockIdx.x * 4 + w;
    const int g0 = blockIdx.y * 3;

    bf16x8 afrag[NK];
    if (AF32) {
        const float* A = (const float*)Ap;
        int arow = rt * 16 + lr;
        int ar = arow < N ? arow : N - 1;
#pragma unroll
        for (int ks = 0; ks < NK; ++ks) {
            const float* ap = A + (size_t)ar * K + ks * 32 + kg * 8;
            float4 a = *(const float4*)ap;
            float4 b = *(const float4*)(ap + 4);
            union { short s[8]; bf16x8 v; } cv;
            cv.s[0] = f2bf(a.x); cv.s[1] = f2bf(a.y); cv.s[2] = f2bf(a.z); cv.s[3] = f2bf(a.w);
            cv.s[4] = f2bf(b.x); cv.s[5] = f2bf(b.y); cv.s[6] = f2bf(b.z); cv.s[7] = f2bf(b.w);
            afrag[ks] = cv.v;
        }
    } else {
        const short* A = (const short*)Ap;
        const short* ap = A + ((size_t)rt * NK * 64 + lane) * 8;
#pragma unroll
        for (int ks = 0; ks < NK; ++ks)
            afrag[ks] = *(const bf16x8*)(ap + ks * 512);
    }

    f32x4 acc[12];
#pragma unroll
    for (int t = 0; t < 12; ++t) acc[t] = (f32x4){0.f, 0.f, 0.f, 0.f};

    const short* bp = Wf + ((size_t)g0 * 4 * NK * 64 + lane) * 8;
#pragma unroll
    for (int tt = 0; tt < 12; ++tt) {
#pragma unroll
        for (int ks = 0; ks < NK; ++ks) {
            bf16x8 bfrag = *(const bf16x8*)(bp + (size_t)(tt * NK + ks) * 512);
            acc[tt] = __builtin_amdgcn_mfma_f32_16x16x32_bf16(afrag[ks], bfrag,
                                                              acc[tt], 0, 0, 0);
        }
    }

    // permuted bias for root slots: slot c' = lr*4 + tt2 holds ch = tt2*16 + lr
    float b0 = bias[lr], b1 = bias[16 + lr], b2 = bias[32 + lr], b3 = bias[48 + lr];

    const int drow0 = rt * 16 + kg * 4;
#pragma unroll
    for (int r = 0; r < 4; ++r) {
        int dr = drow0 + r;
        if (dr >= N) break;
#pragma unroll
        for (int gg = 0; gg < 3; ++gg) {
            int g = g0 + gg;
            if (g < 8) {
                int u0 = pack2bf(acc[gg * 4 + 0][r], acc[gg * 4 + 1][r]);
                int u1 = pack2bf(acc[gg * 4 + 2][r], acc[gg * 4 + 3][r]);
                *(int2*)(hr + (size_t)dr * 512 + g * 64 + lr * 4) = make_int2(u0, u1);
            } else {
                float4 o = make_float4(acc[gg * 4 + 0][r] + b0, acc[gg * 4 + 1][r] + b1,
                                       acc[gg * 4 + 2][r] + b2, acc[gg * 4 + 3][r] + b3);
                *(float4*)(yinit + (size_t)dr * 64 + lr * 4) = o;
            }
        }
    }
}

// ---------------------------------------------------------------------------
// Aggregate: one 64-lane slice per dst node, lane = permuted channel slot.
// Per edge: gather 64 bf16 (128B contiguous) at hr[p.x*64 + lane], fma by inv.
// 4-deep unroll -> 4 independent outstanding gathers.
// Epilogue converts slot -> true channel tc = (l&3)*16 + (l>>2).
// ---------------------------------------------------------------------------
template<bool BF16OUT>
__global__ __launch_bounds__(256) void agg_kernel(const int* __restrict__ offs,
                                                  const int2* __restrict__ edgeP,
                                                  const short* __restrict__ hr,
                                                  const float* __restrict__ init,
                                                  float* __restrict__ outF,
                                                  short* __restrict__ outB, int N)
{
    const int dst = blockIdx.x * 4 + (threadIdx.x >> 6);
    const int l = threadIdx.x & 63;
    if (dst >= N) return;

    const unsigned short* hp = (const unsigned short*)hr;
    float acc = init[(size_t)dst * 64 + l];
    int e0 = offs[dst], e1 = offs[dst + 1];

    int e = e0;
    for (; e + 3 < e1; e += 4) {
        int2 p0 = edgeP[e],     p1 = edgeP[e + 1];
        int2 p2 = edgeP[e + 2], p3 = edgeP[e + 3];
        unsigned short g0 = hp[(size_t)p0.x * 64 + l];
        unsigned short g1 = hp[(size_t)p1.x * 64 + l];
        unsigned short g2 = hp[(size_t)p2.x * 64 + l];
        unsigned short g3 = hp[(size_t)p3.x * 64 + l];
        acc = fmaf(bfval(g0), __int_as_float(p0.y), acc);
        acc = fmaf(bfval(g1), __int_as_float(p1.y), acc);
        acc = fmaf(bfval(g2), __int_as_float(p2.y), acc);
        acc = fmaf(bfval(g3), __int_as_float(p3.y), acc);
    }
    for (; e < e1; ++e) {
        int2 p0 = edgeP[e];
        unsigned short g0 = hp[(size_t)p0.x * 64 + l];
        acc = fmaf(bfval(g0), __int_as_float(p0.y), acc);
    }

    int tc = (l & 3) * 16 + (l >> 2);    // true channel
    if (BF16OUT) {
        // layer-2 A-fragment layout (K=64, NK=2), k = true channel
        int rt2 = dst >> 4, lr2 = dst & 15;
        int ks2 = tc >> 5, kg2 = (tc >> 3) & 3, e2 = tc & 7;
        outB[(((size_t)rt2 * 2 + ks2) * 64 + kg2 * 16 + lr2) * 8 + e2] =
            f2bf(fmaxf(acc, 0.f));
    } else {
        outF[(size_t)dst * 64 + tc] = acc;
    }
}

// ---------------------------------------------------------------------------
extern "C" void kernel_launch(void* const* d_in, const int* in_sizes, int n_in,
                              void* d_out, int out_size, void* d_ws, size_t ws_size,
                              hipStream_t stream)
{
    const float* x      = (const float*)d_in[0];
    const int*   ei     = (const int*)d_in[1];
    const int*   et     = (const int*)d_in[2];
    const float* basis1 = (const float*)d_in[3];
    const float* comp1  = (const float*)d_in[4];
    const float* root1  = (const float*)d_in[5];
    const float* bias1  = (const float*)d_in[6];
    const float* basis2 = (const float*)d_in[7];
    const float* comp2  = (const float*)d_in[8];
    const float* root2  = (const float*)d_in[9];
    const float* bias2  = (const float*)d_in[10];
    float* out = (float*)d_out;

    const int N = in_sizes[0] / 128;
    const int E = in_sizes[2];
    const int* src  = ei;
    const int* dstp = ei + E;

    const int gblk = (N + 63) / 64;
    const int NT   = gblk * 4;
    const int ablk = (N + 3) / 4;

    // -------- workspace carve (256B aligned) --------
    char* p = (char*)d_ws;
    auto carve = [&](size_t bytes) -> char* {
        char* q = p; p += (bytes + 255) & ~(size_t)255; return q;
    };
    int*   cursor  = (int*)carve((size_t)N * 4);          // zeroed
    int*   cnt8    = (int*)carve((size_t)N * NREL * 4);   // zeroed
    char*  zend    = p;
    int*   offs    = (int*)carve((size_t)(N + 1) * 4);
    int*   tsum    = (int*)carve(256 * 4);
    int2*  edgeP   = (int2*)carve((size_t)E * 8);
    short* Wf1     = (short*)carve((size_t)36 * 4 * 64 * 8 * 2);
    short* Wf2     = (short*)carve((size_t)36 * 2 * 64 * 8 * 2);
    float* yinit   = (float*)carve((size_t)N * 64 * 4);
    short* xf2     = (short*)carve((size_t)NT * 2 * 64 * 8 * 2);
    short* hr      = (short*)carve((size_t)N * 512 * 2);

    hipMemsetAsync(cursor, 0, (size_t)(zend - (char*)cursor), stream);

    const int ntiles = (N + SCAN_TILE - 1) / SCAN_TILE;

    // -------- edge bucketing (shared by both layers) --------
    hist_kernel<<<(E + 255) / 256, 256, 0, stream>>>(dstp, et, cnt8, E);
    scan_part<<<ntiles, 256, 0, stream>>>(cnt8, tsum, N);
    scan_mid<<<1, 64, 0, stream>>>(tsum, offs + N, ntiles);
    scan_final<<<ntiles, 256, 0, stream>>>(cnt8, tsum, offs, N);
    scatter_kernel<<<(E + 255) / 256, 256, 0, stream>>>(src, dstp, et, offs, cursor,
                                                        cnt8, edgeP, E);

    // -------- weight prepacks (comp folded in) --------
    wfrag_kernel<128><<<(36 * 4 * 64 + 255) / 256, 256, 0, stream>>>(basis1, root1, comp1, Wf1);
    wfrag_kernel<64><<<(36 * 2 * 64 + 255) / 256, 256, 0, stream>>>(basis2, root2, comp2, Wf2);

    // -------- layer 1 --------
    gemm_mfma<128, true><<<dim3(gblk, 3), 256, 0, stream>>>(x, Wf1, bias1, hr, yinit, N);
    agg_kernel<true><<<ablk, 256, 0, stream>>>(offs, edgeP, hr, yinit, nullptr, xf2, N);

    // -------- layer 2 --------
    gemm_mfma<64, false><<<dim3(gblk, 3), 256, 0, stream>>>(xf2, Wf2, bias2, hr, yinit, N);
    agg_kernel<false><<<ablk, 256, 0, stream>>>(offs, edgeP, hr, yinit, out, nullptr, N);
}

// Round 7
// 192.789 us; speedup vs baseline: 1.2547x; 1.0383x over previous
//
#include <hip/hip_runtime.h>
#include <cstddef>

#define NREL 8
#define SCAN_TILE 4096

typedef __bf16 bf16x8 __attribute__((ext_vector_type(8)));
typedef float f32x4 __attribute__((ext_vector_type(4)));

__device__ __forceinline__ unsigned f2bf_u(float f) {
    unsigned u = __float_as_uint(f);
    u += 0x7FFFu + ((u >> 16) & 1u);           // RNE
    return u >> 16;
}
__device__ __forceinline__ short f2bf(float f) { return (short)f2bf_u(f); }
__device__ __forceinline__ int pack2bf(float lo, float hi) {
    return (int)(f2bf_u(lo) | (f2bf_u(hi) << 16));
}
__device__ __forceinline__ float bfval(unsigned short g) {
    return __uint_as_float((unsigned)g << 16);
}

// ---------------------------------------------------------------------------
// Zero workspace region (replaces pathologically slow graph-captured memset)
// ---------------------------------------------------------------------------
__global__ __launch_bounds__(256) void zero_kernel(int4* __restrict__ p, int n16)
{
    int i = blockIdx.x * 256 + threadIdx.x;
    if (i < n16) p[i] = make_int4(0, 0, 0, 0);
}

// ---------------------------------------------------------------------------
// Histogram per (dst, relation): cnt8[dst*8+rel]++   (cnt8 pre-zeroed)
// ---------------------------------------------------------------------------
__global__ __launch_bounds__(256) void hist_kernel(const int* __restrict__ dst,
                                                   const int* __restrict__ et,
                                                   int* __restrict__ cnt8, int E)
{
    int e = blockIdx.x * 256 + threadIdx.x;
    if (e < E) atomicAdd(&cnt8[dst[e] * NREL + et[e]], 1);
}

// ---------------------------------------------------------------------------
// Scan stage 1: per-tile degree sums
// ---------------------------------------------------------------------------
__global__ __launch_bounds__(256) void scan_part(const int* __restrict__ cnt8,
                                                 int* __restrict__ tsum, int n)
{
    int base = blockIdx.x * SCAN_TILE;
    int s = 0;
    for (int i = threadIdx.x; i < SCAN_TILE; i += 256) {
        int idx = base + i;
        if (idx < n) {
            int4 a = ((const int4*)cnt8)[idx * 2];
            int4 b = ((const int4*)cnt8)[idx * 2 + 1];
            s += a.x + a.y + a.z + a.w + b.x + b.y + b.z + b.w;
        }
    }
    for (int d = 1; d < 64; d <<= 1) s += __shfl_xor(s, d, 64);
    __shared__ int ws[4];
    if ((threadIdx.x & 63) == 0) ws[threadIdx.x >> 6] = s;
    __syncthreads();
    if (threadIdx.x == 0) tsum[blockIdx.x] = ws[0] + ws[1] + ws[2] + ws[3];
}

// ---------------------------------------------------------------------------
// Scan stage 2: serial exclusive scan of tile sums
// ---------------------------------------------------------------------------
__global__ void scan_mid(int* __restrict__ tsum, int* __restrict__ offs_n, int nt)
{
    if (threadIdx.x == 0) {
        int run = 0;
        for (int i = 0; i < nt; ++i) { int t = tsum[i]; tsum[i] = run; run += t; }
        *offs_n = run;
    }
}

// ---------------------------------------------------------------------------
// Scan stage 3: per-tile exclusive scan + tile offset -> offs[n]
// ---------------------------------------------------------------------------
__global__ __launch_bounds__(256) void scan_final(const int* __restrict__ cnt8,
                                                  const int* __restrict__ tsum,
                                                  int* __restrict__ offs, int n)
{
    const int lane = threadIdx.x & 63, wid = threadIdx.x >> 6;
    int base = blockIdx.x * SCAN_TILE + threadIdx.x * 16;
    int v[16]; int s = 0;
#pragma unroll
    for (int j = 0; j < 16; ++j) {
        int idx = base + j;
        int dv = 0;
        if (idx < n) {
            int4 a = ((const int4*)cnt8)[idx * 2];
            int4 b = ((const int4*)cnt8)[idx * 2 + 1];
            dv = a.x + a.y + a.z + a.w + b.x + b.y + b.z + b.w;
        }
        v[j] = dv; s += dv;
    }
    int inc = s;
    for (int d = 1; d < 64; d <<= 1) {
        int t = __shfl_up(inc, d, 64);
        if (lane >= d) inc += t;
    }
    __shared__ int wsum[4];
    if (lane == 63) wsum[wid] = inc;
    __syncthreads();
    int run = tsum[blockIdx.x] + (inc - s);
    for (int k = 0; k < wid; ++k) run += wsum[k];
#pragma unroll
    for (int j = 0; j < 16; ++j) {
        int idx = base + j;
        if (idx < n) offs[idx] = run;
        run += v[j];
    }
}

// ---------------------------------------------------------------------------
// Scatter edges into dst-bucketed order; edgeP = {src*8+rel, bits(1/cnt)}
// ---------------------------------------------------------------------------
__global__ __launch_bounds__(256) void scatter_kernel(const int* __restrict__ src,
                                                      const int* __restrict__ dst,
                                                      const int* __restrict__ et,
                                                      const int* __restrict__ offs,
                                                      int* __restrict__ cursor,
                                                      const int* __restrict__ cnt8,
                                                      int2* __restrict__ edgeP, int E)
{
    int e = blockIdx.x * 256 + threadIdx.x;
    if (e >= E) return;
    int d = dst[e], r = et[e], s = src[e];
    int c = cnt8[d * NREL + r];
    float inv = 1.0f / (float)(c > 1 ? c : 1);
    int pos = offs[d] + atomicAdd(&cursor[d], 1);
    edgeP[pos] = make_int2(s * NREL + r, __float_as_int(inv));
}

// ---------------------------------------------------------------------------
// Prepack W' into MFMA B-fragment order, comp folded in. 36 col-tiles:
//   t = 0..31:  rel rr = t>>2, true channel ch = (t&3)*16 + lr;
//   t = 32..35: root[k][(t-32)*16 + lr]
// Wf[((t*NK+ks)*64 + lane)*8 + e], k = ks*32 + (lane>>4)*8 + e
// ---------------------------------------------------------------------------
template<int K>
__global__ __launch_bounds__(256) void wfrag_kernel(const float* __restrict__ basis,
                                                    const float* __restrict__ root,
                                                    const float* __restrict__ comp,
                                                    short* __restrict__ Wf)
{
    constexpr int NK = K / 32;
    int tid = blockIdx.x * 256 + threadIdx.x;
    if (tid >= 36 * NK * 64) return;
    int lane = tid & 63, slot = tid >> 6;
    int ks = slot % NK, t = slot / NK;
    int kg = lane >> 4, lr = lane & 15;
    int k0 = ks * 32 + kg * 8;
    union { short s[8]; int4 v; } u;
#pragma unroll
    for (int e = 0; e < 8; ++e) {
        int k = k0 + e;
        float v;
        if (t < 32) {
            int rr = t >> 2, ch = (t & 3) * 16 + lr;
            v = comp[rr * 4 + 0] * basis[((size_t)0 * K + k) * 64 + ch]
              + comp[rr * 4 + 1] * basis[((size_t)1 * K + k) * 64 + ch]
              + comp[rr * 4 + 2] * basis[((size_t)2 * K + k) * 64 + ch]
              + comp[rr * 4 + 3] * basis[((size_t)3 * K + k) * 64 + ch];
        } else {
            v = root[(size_t)k * 64 + (t - 32) * 16 + lr];
        }
        u.s[e] = f2bf(v);
    }
    *(int4*)(Wf + (size_t)tid * 8) = u.v;
}

// ---------------------------------------------------------------------------
// Fragment-ize x: f32 row-major -> bf16 A-fragment order, zero-pad rows >= N.
// xf[((rt*NK+ks)*64 + lane)*8 + e] = x[rt*16+(lane&15)][ks*32+(lane>>4)*8+e]
// ---------------------------------------------------------------------------
template<int K>
__global__ __launch_bounds__(256) void afrag_kernel(const float* __restrict__ x,
                                                    short* __restrict__ xf,
                                                    int N, int NT)
{
    constexpr int NK = K / 32;
    int tid = blockIdx.x * 256 + threadIdx.x;
    if (tid >= NT * NK * 64) return;
    int lane = tid & 63, slot = tid >> 6;
    int ks = slot % NK, rt = slot / NK;
    int kg = lane >> 4, lr = lane & 15;
    int row = rt * 16 + lr, k = ks * 32 + kg * 8;
    union { short s[8]; int4 v; } u;
    if (row < N) {
        const float* xp = x + (size_t)row * K + k;
        float4 a = *(const float4*)xp;
        float4 b = *(const float4*)(xp + 4);
        u.s[0] = f2bf(a.x); u.s[1] = f2bf(a.y); u.s[2] = f2bf(a.z); u.s[3] = f2bf(a.w);
        u.s[4] = f2bf(b.x); u.s[5] = f2bf(b.y); u.s[6] = f2bf(b.z); u.s[7] = f2bf(b.w);
    } else {
        u.v = make_int4(0, 0, 0, 0);
    }
    *(int4*)(xf + (size_t)tid * 8) = u.v;
}

// ---------------------------------------------------------------------------
// Fused all-relation + root GEMM: [N,K] x [K,576], split over blockIdx.y.
// Block (bx, by): rows bx*64..+63, 12 col-tiles [by*12, by*12+12).
// B-slice (12*NK KB) staged to LDS ONCE per block -> no per-wave L2 streaming.
// A pre-fragmented bf16 (contiguous 1024B wave loads).
// Epilogue (permuted channel slots c' = lr*4 + tt, true ch = tt*16 + lr):
//   rel groups -> hr[n][g*64 + c'] bf16 (coalesced int2)
//   root group -> yinit[n][c'] = root+bias f32 (coalesced float4)
// ---------------------------------------------------------------------------
template<int K>
__global__ __launch_bounds__(256) void gemm_mfma(const short* __restrict__ xf,
                                                 const short* __restrict__ Wf,
                                                 const float* __restrict__ bias,
                                                 short* __restrict__ hr,
                                                 float* __restrict__ yinit, int N)
{
    constexpr int NK = K / 32;
    __shared__ short lds[12 * NK * 512];

    const int w = threadIdx.x >> 6, lane = threadIdx.x & 63;
    const int kg = lane >> 4, lr = lane & 15;
    const int rt = blockIdx.x * 4 + w;
    const int g0 = blockIdx.y * 3;

    // stage this block's 12-tile B slice into LDS (once)
    {
        const int4* gsrc = (const int4*)(Wf + (size_t)g0 * 4 * NK * 512);
        int4* ldst = (int4*)lds;
#pragma unroll
        for (int i = threadIdx.x; i < 12 * NK * 64; i += 256)
            ldst[i] = gsrc[i];
    }

    bf16x8 afrag[NK];
    const short* ap = xf + ((size_t)rt * NK * 64 + lane) * 8;
#pragma unroll
    for (int ks = 0; ks < NK; ++ks)
        afrag[ks] = *(const bf16x8*)(ap + ks * 512);

    f32x4 acc[12];
#pragma unroll
    for (int t = 0; t < 12; ++t) acc[t] = (f32x4){0.f, 0.f, 0.f, 0.f};

    __syncthreads();

#pragma unroll
    for (int tt = 0; tt < 12; ++tt) {
#pragma unroll
        for (int ks = 0; ks < NK; ++ks) {
            bf16x8 bfrag = *(const bf16x8*)(lds + (tt * NK + ks) * 512 + lane * 8);
            acc[tt] = __builtin_amdgcn_mfma_f32_16x16x32_bf16(afrag[ks], bfrag,
                                                              acc[tt], 0, 0, 0);
        }
    }

    // permuted bias for root slots: slot c' = lr*4 + tt2 holds ch = tt2*16 + lr
    float b0 = bias[lr], b1 = bias[16 + lr], b2 = bias[32 + lr], b3 = bias[48 + lr];

    const int drow0 = rt * 16 + kg * 4;
#pragma unroll
    for (int r = 0; r < 4; ++r) {
        int dr = drow0 + r;
        if (dr >= N) break;
#pragma unroll
        for (int gg = 0; gg < 3; ++gg) {
            int g = g0 + gg;
            if (g < 8) {
                int u0 = pack2bf(acc[gg * 4 + 0][r], acc[gg * 4 + 1][r]);
                int u1 = pack2bf(acc[gg * 4 + 2][r], acc[gg * 4 + 3][r]);
                *(int2*)(hr + (size_t)dr * 512 + g * 64 + lr * 4) = make_int2(u0, u1);
            } else {
                float4 o = make_float4(acc[gg * 4 + 0][r] + b0, acc[gg * 4 + 1][r] + b1,
                                       acc[gg * 4 + 2][r] + b2, acc[gg * 4 + 3][r] + b3);
                *(float4*)(yinit + (size_t)dr * 64 + lr * 4) = o;
            }
        }
    }
}

// ---------------------------------------------------------------------------
// Aggregate: one 64-lane slice per dst node, lane = permuted channel slot.
// Per edge: gather 64 bf16 (128B contiguous) at hr[p.x*64 + lane], fma by inv.
// Epilogue converts slot -> true channel tc = (l&3)*16 + (l>>2).
// ---------------------------------------------------------------------------
template<bool BF16OUT>
__global__ __launch_bounds__(256) void agg_kernel(const int* __restrict__ offs,
                                                  const int2* __restrict__ edgeP,
                                                  const short* __restrict__ hr,
                                                  const float* __restrict__ init,
                                                  float* __restrict__ outF,
                                                  short* __restrict__ outB, int N)
{
    const int dst = blockIdx.x * 4 + (threadIdx.x >> 6);
    const int l = threadIdx.x & 63;
    if (dst >= N) return;

    const unsigned short* hp = (const unsigned short*)hr;
    float acc = init[(size_t)dst * 64 + l];
    int e0 = offs[dst], e1 = offs[dst + 1];

    int e = e0;
    for (; e + 3 < e1; e += 4) {
        int2 p0 = edgeP[e],     p1 = edgeP[e + 1];
        int2 p2 = edgeP[e + 2], p3 = edgeP[e + 3];
        unsigned short g0 = hp[(size_t)p0.x * 64 + l];
        unsigned short g1 = hp[(size_t)p1.x * 64 + l];
        unsigned short g2 = hp[(size_t)p2.x * 64 + l];
        unsigned short g3 = hp[(size_t)p3.x * 64 + l];
        acc = fmaf(bfval(g0), __int_as_float(p0.y), acc);
        acc = fmaf(bfval(g1), __int_as_float(p1.y), acc);
        acc = fmaf(bfval(g2), __int_as_float(p2.y), acc);
        acc = fmaf(bfval(g3), __int_as_float(p3.y), acc);
    }
    for (; e < e1; ++e) {
        int2 p0 = edgeP[e];
        unsigned short g0 = hp[(size_t)p0.x * 64 + l];
        acc = fmaf(bfval(g0), __int_as_float(p0.y), acc);
    }

    int tc = (l & 3) * 16 + (l >> 2);    // true channel
    if (BF16OUT) {
        // layer-2 A-fragment layout (K=64, NK=2), k = true channel
        int rt2 = dst >> 4, lr2 = dst & 15;
        int ks2 = tc >> 5, kg2 = (tc >> 3) & 3, e2 = tc & 7;
        outB[(((size_t)rt2 * 2 + ks2) * 64 + kg2 * 16 + lr2) * 8 + e2] =
            f2bf(fmaxf(acc, 0.f));
    } else {
        outF[(size_t)dst * 64 + tc] = acc;
    }
}

// ---------------------------------------------------------------------------
extern "C" void kernel_launch(void* const* d_in, const int* in_sizes, int n_in,
                              void* d_out, int out_size, void* d_ws, size_t ws_size,
                              hipStream_t stream)
{
    const float* x      = (const float*)d_in[0];
    const int*   ei     = (const int*)d_in[1];
    const int*   et     = (const int*)d_in[2];
    const float* basis1 = (const float*)d_in[3];
    const float* comp1  = (const float*)d_in[4];
    const float* root1  = (const float*)d_in[5];
    const float* bias1  = (const float*)d_in[6];
    const float* basis2 = (const float*)d_in[7];
    const float* comp2  = (const float*)d_in[8];
    const float* root2  = (const float*)d_in[9];
    const float* bias2  = (const float*)d_in[10];
    float* out = (float*)d_out;

    const int N = in_sizes[0] / 128;
    const int E = in_sizes[2];
    const int* src  = ei;
    const int* dstp = ei + E;

    const int gblk = (N + 63) / 64;
    const int NT   = gblk * 4;
    const int ablk = (N + 3) / 4;

    // -------- workspace carve (256B aligned) --------
    char* p = (char*)d_ws;
    auto carve = [&](size_t bytes) -> char* {
        char* q = p; p += (bytes + 255) & ~(size_t)255; return q;
    };
    int*   cursor  = (int*)carve((size_t)N * 4);          // zeroed
    int*   cnt8    = (int*)carve((size_t)N * NREL * 4);   // zeroed
    char*  zend    = p;
    int*   offs    = (int*)carve((size_t)(N + 1) * 4);
    int*   tsum    = (int*)carve(256 * 4);
    int2*  edgeP   = (int2*)carve((size_t)E * 8);
    short* Wf1     = (short*)carve((size_t)36 * 4 * 64 * 8 * 2);
    short* Wf2     = (short*)carve((size_t)36 * 2 * 64 * 8 * 2);
    float* yinit   = (float*)carve((size_t)N * 64 * 4);
    short* xf1     = (short*)carve((size_t)NT * 4 * 64 * 8 * 2);
    short* xf2     = (short*)carve((size_t)NT * 2 * 64 * 8 * 2);
    short* hr      = (short*)carve((size_t)N * 512 * 2);

    const int zn16 = (int)((zend - (char*)cursor) / 16);
    const int ntiles = (N + SCAN_TILE - 1) / SCAN_TILE;

    // -------- prepacks + layer-1 GEMM first (independent of bucketing) -----
    zero_kernel<<<(zn16 + 255) / 256, 256, 0, stream>>>((int4*)cursor, zn16);
    wfrag_kernel<128><<<(36 * 4 * 64 + 255) / 256, 256, 0, stream>>>(basis1, root1, comp1, Wf1);
    wfrag_kernel<64><<<(36 * 2 * 64 + 255) / 256, 256, 0, stream>>>(basis2, root2, comp2, Wf2);
    afrag_kernel<128><<<(NT * 4 * 64 + 255) / 256, 256, 0, stream>>>(x, xf1, N, NT);
    gemm_mfma<128><<<dim3(gblk, 3), 256, 0, stream>>>(xf1, Wf1, bias1, hr, yinit, N);

    // -------- edge bucketing (shared by both layers) --------
    hist_kernel<<<(E + 255) / 256, 256, 0, stream>>>(dstp, et, cnt8, E);
    scan_part<<<ntiles, 256, 0, stream>>>(cnt8, tsum, N);
    scan_mid<<<1, 64, 0, stream>>>(tsum, offs + N, ntiles);
    scan_final<<<ntiles, 256, 0, stream>>>(cnt8, tsum, offs, N);
    scatter_kernel<<<(E + 255) / 256, 256, 0, stream>>>(src, dstp, et, offs, cursor,
                                                        cnt8, edgeP, E);

    // -------- layer 1 aggregate --------
    agg_kernel<true><<<ablk, 256, 0, stream>>>(offs, edgeP, hr, yinit, nullptr, xf2, N);

    // -------- layer 2 --------
    gemm_mfma<64><<<dim3(gblk, 3), 256, 0, stream>>>(xf2, Wf2, bias2, hr, yinit, N);
    agg_kernel<false><<<ablk, 256, 0, stream>>>(offs, edgeP, hr, yinit, out, nullptr, N);
}

// Round 8
// 189.848 us; speedup vs baseline: 1.2742x; 1.0155x over previous
//
#include <hip/hip_runtime.h>
#include <cstddef>

#define NREL 8
#define SCAN_TILE 4096

typedef __bf16 bf16x8 __attribute__((ext_vector_type(8)));
typedef float f32x4 __attribute__((ext_vector_type(4)));

__device__ __forceinline__ unsigned f2bf_u(float f) {
    unsigned u = __float_as_uint(f);
    u += 0x7FFFu + ((u >> 16) & 1u);           // RNE
    return u >> 16;
}
__device__ __forceinline__ short f2bf(float f) { return (short)f2bf_u(f); }
__device__ __forceinline__ int pack2bf(float lo, float hi) {
    return (int)(f2bf_u(lo) | (f2bf_u(hi) << 16));
}
__device__ __forceinline__ float bfval(unsigned short g) {
    return __uint_as_float((unsigned)g << 16);
}

// ---------------------------------------------------------------------------
// Prepack bodies (device functions, shared by prep_kernel regions)
// ---------------------------------------------------------------------------
template<int K>
__device__ __forceinline__ void wfrag_body(const float* __restrict__ basis,
                                           const float* __restrict__ root,
                                           const float* __restrict__ comp,
                                           short* __restrict__ Wf, int tid)
{
    constexpr int NK = K / 32;
    int lane = tid & 63, slot = tid >> 6;
    int ks = slot % NK, t = slot / NK;
    int kg = lane >> 4, lr = lane & 15;
    int k0 = ks * 32 + kg * 8;
    union { short s[8]; int4 v; } u;
#pragma unroll
    for (int e = 0; e < 8; ++e) {
        int k = k0 + e;
        float v;
        if (t < 32) {
            int rr = t >> 2, ch = (t & 3) * 16 + lr;
            v = comp[rr * 4 + 0] * basis[((size_t)0 * K + k) * 64 + ch]
              + comp[rr * 4 + 1] * basis[((size_t)1 * K + k) * 64 + ch]
              + comp[rr * 4 + 2] * basis[((size_t)2 * K + k) * 64 + ch]
              + comp[rr * 4 + 3] * basis[((size_t)3 * K + k) * 64 + ch];
        } else {
            v = root[(size_t)k * 64 + (t - 32) * 16 + lr];
        }
        u.s[e] = f2bf(v);
    }
    *(int4*)(Wf + (size_t)tid * 8) = u.v;
}

__device__ __forceinline__ void afrag_body128(const float* __restrict__ x,
                                              short* __restrict__ xf, int N, int tid)
{
    int lane = tid & 63, slot = tid >> 6;
    int ks = slot & 3, rt = slot >> 2;
    int kg = lane >> 4, lr = lane & 15;
    int row = rt * 16 + lr, k = ks * 32 + kg * 8;
    union { short s[8]; int4 v; } u;
    if (row < N) {
        const float* xp = x + (size_t)row * 128 + k;
        float4 a = *(const float4*)xp;
        float4 b = *(const float4*)(xp + 4);
        u.s[0] = f2bf(a.x); u.s[1] = f2bf(a.y); u.s[2] = f2bf(a.z); u.s[3] = f2bf(a.w);
        u.s[4] = f2bf(b.x); u.s[5] = f2bf(b.y); u.s[6] = f2bf(b.z); u.s[7] = f2bf(b.w);
    } else {
        u.v = make_int4(0, 0, 0, 0);
    }
    *(int4*)(xf + (size_t)tid * 8) = u.v;
}

// ---------------------------------------------------------------------------
// Fused prep: [zero cursor/cnt8 + offs[N]=E] | wfrag1 | wfrag2 | afrag(x)
// partitioned over blockIdx.x
// ---------------------------------------------------------------------------
__global__ __launch_bounds__(256) void prep_kernel(
    const float* __restrict__ basis1, const float* __restrict__ root1,
    const float* __restrict__ comp1,  const float* __restrict__ basis2,
    const float* __restrict__ root2,  const float* __restrict__ comp2,
    const float* __restrict__ x,
    short* __restrict__ Wf1, short* __restrict__ Wf2, short* __restrict__ xf1,
    int4* __restrict__ zp, int zn16, int* __restrict__ offsN,
    int E, int N, int NT)
{
    int b = blockIdx.x;
    const int zb = (zn16 + 255) >> 8;
    if (b < zb) {
        int i = b * 256 + threadIdx.x;
        if (i < zn16) zp[i] = make_int4(0, 0, 0, 0);
        if (b == 0 && threadIdx.x == 0) *offsN = E;
        return;
    }
    b -= zb;
    if (b < 36) { wfrag_body<128>(basis1, root1, comp1, Wf1, b * 256 + threadIdx.x); return; }
    b -= 36;
    if (b < 18) { wfrag_body<64>(basis2, root2, comp2, Wf2, b * 256 + threadIdx.x); return; }
    b -= 18;
    int tid = b * 256 + threadIdx.x;
    if (tid < NT * 256) afrag_body128(x, xf1, N, tid);
}

// ---------------------------------------------------------------------------
// Histogram per (dst, relation): cnt8[dst*8+rel]++   (cnt8 pre-zeroed)
// ---------------------------------------------------------------------------
__global__ __launch_bounds__(256) void hist_kernel(const int* __restrict__ dst,
                                                   const int* __restrict__ et,
                                                   int* __restrict__ cnt8, int E)
{
    int e = blockIdx.x * 256 + threadIdx.x;
    if (e < E) atomicAdd(&cnt8[dst[e] * NREL + et[e]], 1);
}

// ---------------------------------------------------------------------------
// Scan stage 1: per-tile degree sums
// ---------------------------------------------------------------------------
__global__ __launch_bounds__(256) void scan_part(const int* __restrict__ cnt8,
                                                 int* __restrict__ tsum, int n)
{
    int base = blockIdx.x * SCAN_TILE;
    int s = 0;
    for (int i = threadIdx.x; i < SCAN_TILE; i += 256) {
        int idx = base + i;
        if (idx < n) {
            int4 a = ((const int4*)cnt8)[idx * 2];
            int4 b = ((const int4*)cnt8)[idx * 2 + 1];
            s += a.x + a.y + a.z + a.w + b.x + b.y + b.z + b.w;
        }
    }
    for (int d = 1; d < 64; d <<= 1) s += __shfl_xor(s, d, 64);
    __shared__ int ws[4];
    if ((threadIdx.x & 63) == 0) ws[threadIdx.x >> 6] = s;
    __syncthreads();
    if (threadIdx.x == 0) tsum[blockIdx.x] = ws[0] + ws[1] + ws[2] + ws[3];
}

// ---------------------------------------------------------------------------
// Scan stage 2: per-tile exclusive scan; tile base re-derived per block from
// raw tsum (<=13 values) -> offs[n]. (scan_mid eliminated)
// ---------------------------------------------------------------------------
__global__ __launch_bounds__(256) void scan_final(const int* __restrict__ cnt8,
                                                  const int* __restrict__ tsum,
                                                  int* __restrict__ offs, int n)
{
    const int lane = threadIdx.x & 63, wid = threadIdx.x >> 6;
    int tbase = 0;
    for (int i = 0; i < blockIdx.x; ++i) tbase += tsum[i];
    int base = blockIdx.x * SCAN_TILE + threadIdx.x * 16;
    int v[16]; int s = 0;
#pragma unroll
    for (int j = 0; j < 16; ++j) {
        int idx = base + j;
        int dv = 0;
        if (idx < n) {
            int4 a = ((const int4*)cnt8)[idx * 2];
            int4 b = ((const int4*)cnt8)[idx * 2 + 1];
            dv = a.x + a.y + a.z + a.w + b.x + b.y + b.z + b.w;
        }
        v[j] = dv; s += dv;
    }
    int inc = s;
    for (int d = 1; d < 64; d <<= 1) {
        int t = __shfl_up(inc, d, 64);
        if (lane >= d) inc += t;
    }
    __shared__ int wsum[4];
    if (lane == 63) wsum[wid] = inc;
    __syncthreads();
    int run = tbase + (inc - s);
    for (int k = 0; k < wid; ++k) run += wsum[k];
#pragma unroll
    for (int j = 0; j < 16; ++j) {
        int idx = base + j;
        if (idx < n) offs[idx] = run;
        run += v[j];
    }
}

// ---------------------------------------------------------------------------
// Scatter edges into dst-bucketed order; edgeP = {src*8+rel, bits(1/cnt)}
// ---------------------------------------------------------------------------
__global__ __launch_bounds__(256) void scatter_kernel(const int* __restrict__ src,
                                                      const int* __restrict__ dst,
                                                      const int* __restrict__ et,
                                                      const int* __restrict__ offs,
                                                      int* __restrict__ cursor,
                                                      const int* __restrict__ cnt8,
                                                      int2* __restrict__ edgeP, int E)
{
    int e = blockIdx.x * 256 + threadIdx.x;
    if (e >= E) return;
    int d = dst[e], r = et[e], s = src[e];
    int c = cnt8[d * NREL + r];
    float inv = 1.0f / (float)(c > 1 ? c : 1);
    int pos = offs[d] + atomicAdd(&cursor[d], 1);
    edgeP[pos] = make_int2(s * NREL + r, __float_as_int(inv));
}

// ---------------------------------------------------------------------------
// Persistent fused all-relation + root GEMM: [N,K] x [K,576].
// Block (bx, by): col-tiles [by*12, by*12+12) staged to LDS ONCE, then loop
// over row-chunks bx, bx+gridDim.x, ... (amortizes B traffic ~4x).
// Epilogue (permuted channel slots c' = lr*4 + tt, true ch = tt*16 + lr):
//   rel groups -> hr[n][g*64 + c'] bf16 (coalesced int2)
//   root group -> yinit[n][c'] = root+bias f32 (coalesced float4)
// ---------------------------------------------------------------------------
template<int K>
__global__ __launch_bounds__(256) void gemm_mfma(const short* __restrict__ xf,
                                                 const short* __restrict__ Wf,
                                                 const float* __restrict__ bias,
                                                 short* __restrict__ hr,
                                                 float* __restrict__ yinit,
                                                 int N, int gblk)
{
    constexpr int NK = K / 32;
    __shared__ short lds[12 * NK * 512];

    const int w = threadIdx.x >> 6, lane = threadIdx.x & 63;
    const int kg = lane >> 4, lr = lane & 15;
    const int g0 = blockIdx.y * 3;

    // stage this block's 12-tile B slice into LDS (once per block)
    {
        const int4* gsrc = (const int4*)(Wf + (size_t)g0 * 4 * NK * 512);
        int4* ldst = (int4*)lds;
        for (int i = threadIdx.x; i < 12 * NK * 64; i += 256)
            ldst[i] = gsrc[i];
    }

    // permuted bias for root slots: slot c' = lr*4 + tt2 holds ch = tt2*16 + lr
    float b0 = bias[lr], b1 = bias[16 + lr], b2 = bias[32 + lr], b3 = bias[48 + lr];

    __syncthreads();

    for (int bx = blockIdx.x; bx < gblk; bx += gridDim.x) {
        const int rt = bx * 4 + w;

        bf16x8 afrag[NK];
        const short* ap = xf + ((size_t)rt * NK * 64 + lane) * 8;
#pragma unroll
        for (int ks = 0; ks < NK; ++ks)
            afrag[ks] = *(const bf16x8*)(ap + ks * 512);

        f32x4 acc[12];
#pragma unroll
        for (int t = 0; t < 12; ++t) acc[t] = (f32x4){0.f, 0.f, 0.f, 0.f};

#pragma unroll
        for (int tt = 0; tt < 12; ++tt) {
#pragma unroll
            for (int ks = 0; ks < NK; ++ks) {
                bf16x8 bfrag = *(const bf16x8*)(lds + (tt * NK + ks) * 512 + lane * 8);
                acc[tt] = __builtin_amdgcn_mfma_f32_16x16x32_bf16(afrag[ks], bfrag,
                                                                  acc[tt], 0, 0, 0);
            }
        }

        const int drow0 = rt * 16 + kg * 4;
#pragma unroll
        for (int r = 0; r < 4; ++r) {
            int dr = drow0 + r;
            if (dr >= N) break;
#pragma unroll
            for (int gg = 0; gg < 3; ++gg) {
                int g = g0 + gg;
                if (g < 8) {
                    int u0 = pack2bf(acc[gg * 4 + 0][r], acc[gg * 4 + 1][r]);
                    int u1 = pack2bf(acc[gg * 4 + 2][r], acc[gg * 4 + 3][r]);
                    *(int2*)(hr + (size_t)dr * 512 + g * 64 + lr * 4) = make_int2(u0, u1);
                } else {
                    float4 o = make_float4(acc[gg * 4 + 0][r] + b0, acc[gg * 4 + 1][r] + b1,
                                           acc[gg * 4 + 2][r] + b2, acc[gg * 4 + 3][r] + b3);
                    *(float4*)(yinit + (size_t)dr * 64 + lr * 4) = o;
                }
            }
        }
    }
}

// ---------------------------------------------------------------------------
// Aggregate: one 64-lane slice per dst node, lane = permuted channel slot.
// Per edge: gather 64 bf16 (128B contiguous) at hr[p.x*64 + lane], fma by inv.
// Epilogue converts slot -> true channel tc = (l&3)*16 + (l>>2).
// ---------------------------------------------------------------------------
template<bool BF16OUT>
__global__ __launch_bounds__(256) void agg_kernel(const int* __restrict__ offs,
                                                  const int2* __restrict__ edgeP,
                                                  const short* __restrict__ hr,
                                                  const float* __restrict__ init,
                                                  float* __restrict__ outF,
                                                  short* __restrict__ outB, int N)
{
    const int dst = blockIdx.x * 4 + (threadIdx.x >> 6);
    const int l = threadIdx.x & 63;
    if (dst >= N) return;

    const unsigned short* hp = (const unsigned short*)hr;
    float acc = init[(size_t)dst * 64 + l];
    int e0 = offs[dst], e1 = offs[dst + 1];

    int e = e0;
    for (; e + 3 < e1; e += 4) {
        int2 p0 = edgeP[e],     p1 = edgeP[e + 1];
        int2 p2 = edgeP[e + 2], p3 = edgeP[e + 3];
        unsigned short g0 = hp[(size_t)p0.x * 64 + l];
        unsigned short g1 = hp[(size_t)p1.x * 64 + l];
        unsigned short g2 = hp[(size_t)p2.x * 64 + l];
        unsigned short g3 = hp[(size_t)p3.x * 64 + l];
        acc = fmaf(bfval(g0), __int_as_float(p0.y), acc);
        acc = fmaf(bfval(g1), __int_as_float(p1.y), acc);
        acc = fmaf(bfval(g2), __int_as_float(p2.y), acc);
        acc = fmaf(bfval(g3), __int_as_float(p3.y), acc);
    }
    for (; e < e1; ++e) {
        int2 p0 = edgeP[e];
        unsigned short g0 = hp[(size_t)p0.x * 64 + l];
        acc = fmaf(bfval(g0), __int_as_float(p0.y), acc);
    }

    int tc = (l & 3) * 16 + (l >> 2);    // true channel
    if (BF16OUT) {
        // layer-2 A-fragment layout (K=64, NK=2), k = true channel
        int rt2 = dst >> 4, lr2 = dst & 15;
        int ks2 = tc >> 5, kg2 = (tc >> 3) & 3, e2 = tc & 7;
        outB[(((size_t)rt2 * 2 + ks2) * 64 + kg2 * 16 + lr2) * 8 + e2] =
            f2bf(fmaxf(acc, 0.f));
    } else {
        outF[(size_t)dst * 64 + tc] = acc;
    }
}

// ---------------------------------------------------------------------------
extern "C" void kernel_launch(void* const* d_in, const int* in_sizes, int n_in,
                              void* d_out, int out_size, void* d_ws, size_t ws_size,
                              hipStream_t stream)
{
    const float* x      = (const float*)d_in[0];
    const int*   ei     = (const int*)d_in[1];
    const int*   et     = (const int*)d_in[2];
    const float* basis1 = (const float*)d_in[3];
    const float* comp1  = (const float*)d_in[4];
    const float* root1  = (const float*)d_in[5];
    const float* bias1  = (const float*)d_in[6];
    const float* basis2 = (const float*)d_in[7];
    const float* comp2  = (const float*)d_in[8];
    const float* root2  = (const float*)d_in[9];
    const float* bias2  = (const float*)d_in[10];
    float* out = (float*)d_out;

    const int N = in_sizes[0] / 128;
    const int E = in_sizes[2];
    const int* src  = ei;
    const int* dstp = ei + E;

    const int gblk = (N + 63) / 64;
    const int NT   = gblk * 4;
    const int ablk = (N + 3) / 4;

    // -------- workspace carve (256B aligned) --------
    char* p = (char*)d_ws;
    auto carve = [&](size_t bytes) -> char* {
        char* q = p; p += (bytes + 255) & ~(size_t)255; return q;
    };
    int*   cursor  = (int*)carve((size_t)N * 4);          // zeroed
    int*   cnt8    = (int*)carve((size_t)N * NREL * 4);   // zeroed
    char*  zend    = p;
    int*   offs    = (int*)carve((size_t)(N + 1) * 4);
    int*   tsum    = (int*)carve(256 * 4);
    int2*  edgeP   = (int2*)carve((size_t)E * 8);
    short* Wf1     = (short*)carve((size_t)36 * 4 * 64 * 8 * 2);
    short* Wf2     = (short*)carve((size_t)36 * 2 * 64 * 8 * 2);
    float* yinit   = (float*)carve((size_t)N * 64 * 4);
    short* xf1     = (short*)carve((size_t)NT * 4 * 64 * 8 * 2);
    short* xf2     = (short*)carve((size_t)NT * 2 * 64 * 8 * 2);
    short* hr      = (short*)carve((size_t)N * 512 * 2);

    const int zn16 = (int)((zend - (char*)cursor) / 16);
    const int zb   = (zn16 + 255) / 256;
    const int ntiles = (N + SCAN_TILE - 1) / SCAN_TILE;

    // -------- fused prep: zero | wfrag1 | wfrag2 | afrag --------
    prep_kernel<<<zb + 36 + 18 + NT, 256, 0, stream>>>(
        basis1, root1, comp1, basis2, root2, comp2, x,
        Wf1, Wf2, xf1, (int4*)cursor, zn16, offs + N, E, N, NT);

    // -------- edge bucketing (shared by both layers) --------
    hist_kernel<<<(E + 255) / 256, 256, 0, stream>>>(dstp, et, cnt8, E);
    scan_part<<<ntiles, 256, 0, stream>>>(cnt8, tsum, N);
    scan_final<<<ntiles, 256, 0, stream>>>(cnt8, tsum, offs, N);
    scatter_kernel<<<(E + 255) / 256, 256, 0, stream>>>(src, dstp, et, offs, cursor,
                                                        cnt8, edgeP, E);

    // -------- layer 1 --------
    gemm_mfma<128><<<dim3(196, 3), 256, 0, stream>>>(xf1, Wf1, bias1, hr, yinit, N, gblk);
    agg_kernel<true><<<ablk, 256, 0, stream>>>(offs, edgeP, hr, yinit, nullptr, xf2, N);

    // -------- layer 2 --------
    gemm_mfma<64><<<dim3(196, 3), 256, 0, stream>>>(xf2, Wf2, bias2, hr, yinit, N, gblk);
    agg_kernel<false><<<ablk, 256, 0, stream>>>(offs, edgeP, hr, yinit, out, nullptr, N);
}